// Round 3
// baseline (104.793 us; speedup 1.0000x reference)
//
#include <hip/hip_runtime.h>

namespace {

constexpr int L     = 128;
constexpr int NANG  = 120;
constexpr int NPTS  = 16;                 // 4x4 (x,y) tile
constexpr size_t H16_BYTES = (size_t)2 * NANG * L * L * 2;   // 7,864,320

typedef __fp16 f16x2 __attribute__((ext_vector_type(2)));
typedef __fp16 f16x4 __attribute__((ext_vector_type(4)));
typedef float  f32x4 __attribute__((ext_vector_type(4)));

// Prepass: image f32 -> f16 (round-toward-zero, identical bits to the f32
// path's cvt_pkrtz of B) into workspace.
__global__ __launch_bounds__(256) void cvt16_kernel(const float* __restrict__ in,
                                                    unsigned* __restrict__ out) {
    const int i = ((int)blockIdx.x * 256 + (int)threadIdx.x) * 4;
    const float4 v = *reinterpret_cast<const float4*>(in + i);
    f16x2 a = __builtin_amdgcn_cvt_pkrtz(v.x, v.y);
    f16x2 b = __builtin_amdgcn_cvt_pkrtz(v.z, v.w);
    uint2 st;
    st.x = *reinterpret_cast<unsigned*>(&a);
    st.y = *reinterpret_cast<unsigned*>(&b);
    *reinterpret_cast<uint2*>(out + i / 2) = st;
}

// Block: 512 thr = 8 waves. Tile: 4(x) x 4(y) = 16 points, both b, all 128 z.
// Wave = (b, zhalf, aset): aset splits the 60 angle-pairs in half so each
// lane can load dwordx2 (4 f16 z's) -> half the VMEM instructions, 2x the
// bytes in flight per buffer, identical cache-line footprint (no dup).
// K-packing: one 16x16x16 MFMA holds TWO angles (8-row windows): quads 0,1 ->
// angle 2p, quads 2,3 -> angle 2p+1. Morton-chunked grid: XCD c owns Morton
// ids [128c,128c+128) = a 64x32-point rectangle, all co-resident.
// Epilogue: aset-1 waves dump acc into retired aftab LDS; aset-0 waves
// add + normalize + float4 store.
template <bool F16>
__global__ __launch_bounds__(512, 8) void bp_kernel(
    const void* __restrict__ imgv,     // f16: [2,120,128,128] half; f32: float
    const float* __restrict__ angles,  // [120] deg
    float* __restrict__ out)           // [2,128,128,128] f32
{
    constexpr unsigned SLICE = F16 ? 32768u : 65536u;
    constexpr unsigned ROWB  = F16 ? 256u  : 512u;
    constexpr int      RSH   = F16 ? 8 : 9;          // row -> byte shift

    __shared__ alignas(16) unsigned long long aftab[NANG * 2 * NPTS]; // 30 KiB
    __shared__ float2   acs[NANG];
    __shared__ unsigned arloB[NANG];   // (window first row) << RSH (byte offset)
    __shared__ alignas(16) float nrmtab[NPTS];

    const int tid = threadIdx.x;
    // Morton deinterleave of the per-XCD-contiguous id.
    const int bid = (int)blockIdx.x;
    const int n   = ((bid & 7) << 7) | (bid >> 3);
    int xt = 0, yt = 0;
#pragma unroll
    for (int i = 0; i < 5; ++i) {
        xt |= ((n >> (2 * i)) & 1) << i;
        yt |= ((n >> (2 * i + 1)) & 1) << i;
    }
    const int xb = xt * 4, yb = yt * 4;
    const float cx = (L - 1) * 0.5f;

    // ---- Phase 0: per-angle rotation params + 8-row window floor ----
    if (tid < NANG) {
        const float phi = -angles[tid] * 0.017453292519943295f;
        float s, c;
        sincosf(phi, &s, &c);
        const float X0 = (float)xb - cx,  X1 = (float)(xb + 3) - cx;
        const float Y0 = (float)yb - cx,  Y1 = (float)(yb + 3) - cx;
        const float a00 = -s * X0 + c * Y0 + cx;
        const float a01 = -s * X0 + c * Y1 + cx;
        const float a10 = -s * X1 + c * Y0 + cx;
        const float a11 = -s * X1 + c * Y1 + cx;
        const float symin = fminf(fminf(a00, a01), fminf(a10, a11));
        acs[tid]   = make_float2(c, s);
        // span (incl. bilinear tap) <= 7 rows; -1 margin; rlo <= 120 keeps
        // rows rlo..rlo+7 in-bounds always.
        arloB[tid] = (unsigned)min(max((int)floorf(symin) - 1, 0), 120) << RSH;
    }
    if (tid < NPTS) nrmtab[tid] = 0.f;
    __syncthreads();

    // ---- Phase 1: per-(angle,point) A-fragments + norm partial sums ----
    float wsum = 0.f;
#pragma unroll
    for (int k = 0; k < 4; ++k) {
        const int e = tid + k * 512;            // e = a*16 + p (p = tid&15 fixed)
        if (e < NANG * NPTS) {
            const int p = e & 15;
            const int a = e >> 4;
            const float2 cs = acs[a];
            const int rlo = (int)(arloB[a] >> RSH);
            const float X = (float)(xb + (p >> 2)) - cx;
            const float Y = (float)(yb + (p & 3)) - cx;
            const float sx =  cs.x * X + cs.y * Y + cx;
            const float sy = -cs.y * X + cs.x * Y + cx;
            const float x0f = floorf(sx), y0f = floorf(sy);
            const float wx = sx - x0f,    wy = sy - y0f;
            const int x0 = (int)x0f, y0 = (int)y0f;
            const float mx0 = (x0 >= 0  && x0 <  L)     ? 1.f : 0.f;
            const float mx1 = (x0 >= -1 && x0 <= L - 2) ? 1.f : 0.f;
            const float my0 = (y0 >= 0  && y0 <  L)     ? 1.f : 0.f;
            const float my1 = (y0 >= -1 && y0 <= L - 2) ? 1.f : 0.f;
            const float A   = (1.f - wx) * mx0 + wx * mx1;
            float w0f = (1.f - wy) * my0 * A;
            float w1f = wy * my1 * A;
            const int y0c = min(max(y0, 0), L - 1);
            const int y1c = min(max(y0 + 1, 0), L - 1);
            const int s0  = min(max(y0c - rlo, 0), 7);
            const int s1  = min(max(y1c - rlo, 0), 7);
            if (s0 == s1) { w0f += w1f; w1f = 0.f; }   // clamp collision fold
            f16x2 wh = __builtin_amdgcn_cvt_pkrtz(w0f, w1f);
            const unsigned wbits = *reinterpret_cast<unsigned*>(&wh);
            const unsigned t  = (unsigned)s0 & 3u;
            const int      q0 = s0 >> 2;                  // 0 or 1
            const unsigned long long W = (unsigned long long)wbits << (t * 16u);
            const unsigned long long spill =
                (t == 3u) ? (unsigned long long)(wbits >> 16) : 0ull;
            aftab[a * 32 + p]      = (q0 == 0) ? W : 0ull;      // lq=0 half
            aftab[a * 32 + 16 + p] = (q0 == 1) ? W : spill;     // lq=1 half
            wsum += w0f + w1f;
        }
    }
    atomicAdd(&nrmtab[tid & 15], wsum);
    __syncthreads();

    const int wave  = tid >> 6;
    const int lane  = tid & 63;
    const int quad  = lane >> 4;
    const int lhalf = lane & 15;
    const int sel   = quad >> 1;           // which angle of the pair
    const int lq    = quad & 1;            // which 4-row K-subgroup
    const int b     = wave & 1;
    const int zh    = (wave >> 1) & 1;     // z half (64 z's)
    const int aset  = wave >> 2;           // angle-pair half (30 pairs)
    const char* __restrict__ imgc = (const char*)imgv;

    const unsigned bbase_s = __builtin_amdgcn_readfirstlane((unsigned)(b * NANG) * SLICE);
    const unsigned voffc = (unsigned)sel * SLICE
                         + (unsigned)(lq * 4) * ROWB
                         + (unsigned)(zh * 64 + 4 * lhalf) * (F16 ? 2u : 4u);
    const int p0 = aset * 30;

    f32x4 acc[4] = {};   // z = zh*64 + 4*lhalf + k

    auto issue = [&](uint2* r, float4* rfp, unsigned long long& afs, int i) {
        const int pr = p0 + i;
        afs = aftab[pr * 64 + lane];           // linear, conflict-free ds_read
        const unsigned rlB = arloB[2 * pr + sel];
        const char* pa = imgc + (bbase_s + (unsigned)(2 * pr) * SLICE); // SGPR base
        const unsigned voff = voffc + rlB;
        if constexpr (F16) {
#pragma unroll
            for (int j = 0; j < 4; ++j)        // row lq*4+j, imm j*256
                r[j] = *(const uint2*)(pa + (voff + (unsigned)j * ROWB));
        } else {
#pragma unroll
            for (int j = 0; j < 4; ++j)
                rfp[j] = *(const float4*)(pa + (voff + (unsigned)j * ROWB));
        }
    };
    auto compute = [&](const uint2* r, const float4* rfp, unsigned long long afu) {
        union { unsigned long long u; f16x4 v; } c; c.u = afu;
        f16x4 bf[4];
        if constexpr (F16) {
            union { unsigned u[2]; f16x4 v; } t;
            t.u[0] = __builtin_amdgcn_perm(r[1].x, r[0].x, 0x05040100u);
            t.u[1] = __builtin_amdgcn_perm(r[3].x, r[2].x, 0x05040100u);
            bf[0] = t.v;
            t.u[0] = __builtin_amdgcn_perm(r[1].x, r[0].x, 0x07060302u);
            t.u[1] = __builtin_amdgcn_perm(r[3].x, r[2].x, 0x07060302u);
            bf[1] = t.v;
            t.u[0] = __builtin_amdgcn_perm(r[1].y, r[0].y, 0x05040100u);
            t.u[1] = __builtin_amdgcn_perm(r[3].y, r[2].y, 0x05040100u);
            bf[2] = t.v;
            t.u[0] = __builtin_amdgcn_perm(r[1].y, r[0].y, 0x07060302u);
            t.u[1] = __builtin_amdgcn_perm(r[3].y, r[2].y, 0x07060302u);
            bf[3] = t.v;
        } else {
#pragma unroll
            for (int k = 0; k < 4; ++k) {
                const f16x2 ha = __builtin_amdgcn_cvt_pkrtz(rfp[0][k], rfp[1][k]);
                const f16x2 hb = __builtin_amdgcn_cvt_pkrtz(rfp[2][k], rfp[3][k]);
                bf[k] = f16x4{ha.x, ha.y, hb.x, hb.y};
            }
        }
#pragma unroll
        for (int k = 0; k < 4; ++k)
            acc[k] = __builtin_amdgcn_mfma_f32_16x16x16f16(c.v, bf[k], acc[k], 0, 0, 0);
    };

    // ---- Main loop: 3-buffer pipeline over this wave's 30 pairs ----
    uint2  ru0[4], ru1[4], ru2[4];
    float4 rf0[4], rf1[4], rf2[4];
    unsigned long long af0, af1, af2;

    issue(ru0, rf0, af0, 0);
    issue(ru1, rf1, af1, 1);

    for (int i = 0; i < 30; i += 3) {
        if (i + 2 < 30) issue(ru2, rf2, af2, i + 2);
        compute(ru0, rf0, af0);
        if (i + 3 < 30) issue(ru0, rf0, af0, i + 3);
        compute(ru1, rf1, af1);
        if (i + 4 < 30) issue(ru1, rf1, af1, i + 4);
        compute(ru2, rf2, af2);
    }

    // ---- Cross-wave reduction (aset 1 -> aset 0) in retired aftab space ----
    __syncthreads();                       // everyone done with aftab
    float4* red = reinterpret_cast<float4*>(aftab);   // 16 KiB of 30 KiB
    if (aset == 1) {
#pragma unroll
        for (int k = 0; k < 4; ++k)
            red[k * 256 + (wave & 3) * 64 + lane] = *(const float4*)&acc[k];
    }
    __syncthreads();
    if (aset == 0) {
#pragma unroll
        for (int k = 0; k < 4; ++k) {
            const float4 o = red[k * 256 + (wave & 3) * 64 + lane];
            acc[k][0] += o.x; acc[k][1] += o.y; acc[k][2] += o.z; acc[k][3] += o.w;
        }
        // ---- Epilogue: point p = quad*4+r, z = zh*64 + 4*lhalf + k ----
        const float4 nrm4 = *(const float4*)&nrmtab[quad * 4];
        const float iv[4] = { 1.f / (nrm4.x + 1e-11f), 1.f / (nrm4.y + 1e-11f),
                              1.f / (nrm4.z + 1e-11f), 1.f / (nrm4.w + 1e-11f) };
        const int zb = zh * 64 + 4 * lhalf;
#pragma unroll
        for (int r = 0; r < 4; ++r) {
            const int pnt = quad * 4 + r;
            const int x = xb + (pnt >> 2);
            const int y = yb + (pnt & 3);
            const float4 o = make_float4(acc[0][r] * iv[r], acc[1][r] * iv[r],
                                         acc[2][r] * iv[r], acc[3][r] * iv[r]);
            *reinterpret_cast<float4*>(&out[(((size_t)(b * L + x)) * L + y) * L + zb]) = o;
        }
    }
}

} // namespace

extern "C" void kernel_launch(void* const* d_in, const int* in_sizes, int n_in,
                              void* d_out, int out_size, void* d_ws, size_t ws_size,
                              hipStream_t stream) {
    const float* image  = (const float*)d_in[0];
    const float* angles = (const float*)d_in[1];
    float* out = (float*)d_out;
    (void)in_sizes; (void)n_in; (void)out_size;

    dim3 grid(1024);   // 32x32 tiles of 4x4 = exactly 4 blocks per CU
    if (d_ws != nullptr && ws_size >= H16_BYTES) {
        cvt16_kernel<<<dim3(3840), 256, 0, stream>>>(image, (unsigned*)d_ws);
        bp_kernel<true><<<grid, 512, 0, stream>>>(d_ws, angles, out);
    } else {
        bp_kernel<false><<<grid, 512, 0, stream>>>(image, angles, out);
    }
}